// Round 1
// baseline (544.235 us; speedup 1.0000x reference)
//
#include <hip/hip_runtime.h>

#define C 128
#define G 8
#define KNN 16
#define EPS 1e-5f

// ---------------------------------------------------------------------------
// Kernel 1: fused k,v projection over context rows.
//   k = relu(bn(x@Wk + bk)), v = x@Wv + bv
// grid: N/ROWS blocks, 256 threads. Register tile: 4 rows x 1 col x 2 outputs.
// ---------------------------------------------------------------------------
template <int ROWS>
__global__ __launch_bounds__(256) void kv_kernel(
    const float* __restrict__ X,
    const float* __restrict__ Wk, const float* __restrict__ bk,
    const float* __restrict__ gk, const float* __restrict__ betak,
    const float* __restrict__ Wv, const float* __restrict__ bv,
    float* __restrict__ kout, float* __restrict__ vout)
{
    __shared__ float xs[ROWS * C];
    const int t = threadIdx.x;
    const long long row0 = (long long)blockIdx.x * ROWS;

    // stage the x tile (contiguous ROWS*C floats) via float4
    {
        const float4* src = (const float4*)(X + row0 * C);
        float4* dst = (float4*)xs;
        const int nv4 = ROWS * C / 4;
        for (int i = t; i < nv4; i += 256) dst[i] = src[i];
    }
    __syncthreads();

    const int c  = t & (C - 1);
    const int rh = t >> 7;            // 0..1
    const int RPT = ROWS / 2;         // 4 rows per thread
    const int r0 = rh * RPT;

    float acck[RPT], accv[RPT];
#pragma unroll
    for (int r = 0; r < RPT; r++) { acck[r] = 0.f; accv[r] = 0.f; }

#pragma unroll 4
    for (int i = 0; i < C; i++) {
        const float wk = Wk[i * C + c];
        const float wv = Wv[i * C + c];
#pragma unroll
        for (int r = 0; r < RPT; r++) {
            const float x = xs[(r0 + r) * C + i];   // wave-uniform addr -> LDS broadcast
            acck[r] = fmaf(x, wk, acck[r]);
            accv[r] = fmaf(x, wv, accv[r]);
        }
    }

    const float s  = gk[c] * rsqrtf(1.f + EPS);
    const float tb = betak[c];
    const float bkc = bk[c], bvc = bv[c];
#pragma unroll
    for (int r = 0; r < RPT; r++) {
        const long long row = row0 + r0 + r;
        float yk = (acck[r] + bkc) * s + tb;
        kout[row * C + c] = yk > 0.f ? yk : 0.f;
        vout[row * C + c] = accv[r] + bvc;
    }
}

// ---------------------------------------------------------------------------
// Kernel 2: q projection.  q = relu(bn(x@Wq + bq))
// ---------------------------------------------------------------------------
template <int ROWS>
__global__ __launch_bounds__(256) void q_kernel(
    const float* __restrict__ X,
    const float* __restrict__ W, const float* __restrict__ b,
    const float* __restrict__ g, const float* __restrict__ beta,
    float* __restrict__ out)
{
    __shared__ float xs[ROWS * C];
    const int t = threadIdx.x;
    const long long row0 = (long long)blockIdx.x * ROWS;
    {
        const float4* src = (const float4*)(X + row0 * C);
        float4* dst = (float4*)xs;
        const int nv4 = ROWS * C / 4;
        for (int i = t; i < nv4; i += 256) dst[i] = src[i];
    }
    __syncthreads();

    const int c  = t & (C - 1);
    const int rh = t >> 7;
    const int RPT = ROWS / 2;
    const int r0 = rh * RPT;

    float acc[RPT];
#pragma unroll
    for (int r = 0; r < RPT; r++) acc[r] = 0.f;

#pragma unroll 4
    for (int i = 0; i < C; i++) {
        const float w = W[i * C + c];
#pragma unroll
        for (int r = 0; r < RPT; r++)
            acc[r] = fmaf(xs[(r0 + r) * C + i], w, acc[r]);
    }

    const float s  = g[c] * rsqrtf(1.f + EPS);
    const float tb = beta[c];
    const float bc = b[c];
#pragma unroll
    for (int r = 0; r < RPT; r++) {
        const long long row = row0 + r0 + r;
        float y = (acc[r] + bc) * s + tb;
        out[row * C + c] = y > 0.f ? y : 0.f;
    }
}

// ---------------------------------------------------------------------------
// Kernel 3: per-query attention. One block (256 thr) per query m.
// ---------------------------------------------------------------------------
__global__ __launch_bounds__(256) void attn_kernel(
    const float* __restrict__ qbuf,   // M x C
    const float* __restrict__ kbuf,   // N x C
    const float* __restrict__ vbuf,   // N x C
    const float* __restrict__ qcoord, // M x 3
    const float* __restrict__ ccoord, // N x 3
    const float* __restrict__ Wp1, const float* __restrict__ bp1,
    const float* __restrict__ gp1, const float* __restrict__ betap1,
    const float* __restrict__ Wp2, const float* __restrict__ bp2,
    const float* __restrict__ Ww1, const float* __restrict__ bw1,
    const float* __restrict__ gw1, const float* __restrict__ betaw1,
    const float* __restrict__ Ww2, const float* __restrict__ bw2,
    const int* __restrict__ knn,      // M x KNN
    float* __restrict__ out)          // M x C
{
    const int m = blockIdx.x;
    const int t = threadIdx.x;
    const int CP = C + 4;             // padded stride: stage-3 reads at 8 distinct banks

    __shared__ float qs[C];
    __shared__ float px[KNN], py[KNN], pz[KNN], mfs[KNN];
    __shared__ int   idxs[KNN];
    __shared__ float h1[KNN * C];     // read wave-uniform -> broadcast, no pad needed
    __shared__ float rel[KNN * (C + 4)];
    __shared__ float val[KNN * (C + 4)];
    __shared__ float w1s[C * G];
    __shared__ float hws[KNN * G];
    __shared__ float wl[KNN * G];
    __shared__ float wfin[KNN * G];

    // ---- stage 0: q row, Ww1 tile, neighbor indices / relative positions ----
    if (t < C) qs[t] = qbuf[(long long)m * C + t];
    for (int i = t; i < C * G; i += 256) w1s[i] = Ww1[i];
    if (t < KNN) {
        const int ii = knn[m * KNN + t];
        const float mf = ii >= 0 ? 1.f : 0.f;
        const int i0 = ii >= 0 ? ii : 0;
        idxs[t] = i0;
        mfs[t] = mf;
        const float qx = qcoord[m * 3 + 0];
        const float qy = qcoord[m * 3 + 1];
        const float qz = qcoord[m * 3 + 2];
        px[t] = (ccoord[(long long)i0 * 3 + 0] - qx) * mf;
        py[t] = (ccoord[(long long)i0 * 3 + 1] - qy) * mf;
        pz[t] = (ccoord[(long long)i0 * 3 + 2] - qz) * mf;
    }
    __syncthreads();

    // ---- stage 1: h1[j][i] = relu(bn(pos_j . Wp1[:,i] + bp1)) ----
    {
        const int i  = t & (C - 1);
        const int j0 = (t >> 7) * (KNN / 2);
        const float w0 = Wp1[0 * C + i];
        const float w1 = Wp1[1 * C + i];
        const float w2 = Wp1[2 * C + i];
        const float s  = gp1[i] * rsqrtf(1.f + EPS);
        const float tb = betap1[i];
        const float bb = bp1[i];
#pragma unroll
        for (int j = 0; j < KNN / 2; j++) {
            const int jj = j0 + j;
            float y = fmaf(px[jj], w0, fmaf(py[jj], w1, fmaf(pz[jj], w2, bb)));
            y = y * s + tb;
            h1[jj * C + i] = y > 0.f ? y : 0.f;
        }
    }
    __syncthreads();

    // ---- stage 2: peb = h1 @ Wp2 + bp2;  rel = kg - q + peb; val = vg + peb ----
    {
        const int c  = t & (C - 1);
        const int j0 = (t >> 7) * (KNN / 2);   // 8 neighbors per thread

        // prefetch gathers (independent of the GEMM loop -> issued early)
        float kg[KNN / 2], vg[KNN / 2];
#pragma unroll
        for (int j = 0; j < KNN / 2; j++) {
            const long long row = idxs[j0 + j];
            kg[j] = kbuf[row * C + c];
            vg[j] = vbuf[row * C + c];
        }

        float acc[KNN / 2];
        const float bb = bp2[c];
#pragma unroll
        for (int j = 0; j < KNN / 2; j++) acc[j] = bb;

#pragma unroll 4
        for (int i = 0; i < C; i++) {
            const float w = Wp2[i * C + c];
#pragma unroll
            for (int j = 0; j < KNN / 2; j++)
                acc[j] = fmaf(h1[(j0 + j) * C + i], w, acc[j]);  // broadcast LDS read
        }

        const float qc = qs[c];
#pragma unroll
        for (int j = 0; j < KNN / 2; j++) {
            const int jj = j0 + j;
            const float mf = mfs[jj];
            const float peb = acc[j];
            rel[jj * CP + c] = kg[j] * mf - qc + peb;
            val[jj * CP + c] = vg[j] * mf + peb;
        }
    }
    __syncthreads();

    // ---- stage 3a: hw = relu(bn(rel @ Ww1 + bw1)) ----
    if (t < KNN * G) {
        const int j = t >> 3, g = t & (G - 1);
        float acc = 0.f;
        for (int cc = 0; cc < C; cc++)
            acc = fmaf(rel[j * CP + cc], w1s[cc * G + g], acc);
        const float s = gw1[g] * rsqrtf(1.f + EPS);
        float y = (acc + bw1[g]) * s + betaw1[g];
        hws[j * G + g] = y > 0.f ? y : 0.f;
    }
    __syncthreads();

    // ---- stage 3b: logits = hw @ Ww2 + bw2 ----
    if (t < KNN * G) {
        const int j = t >> 3, g2 = t & (G - 1);
        float acc = bw2[g2];
#pragma unroll
        for (int g = 0; g < G; g++)
            acc = fmaf(hws[j * G + g], Ww2[g * G + g2], acc);
        wl[j * G + g2] = acc;
    }
    __syncthreads();

    // ---- softmax over neighbors (per group), then * mask ----
    if (t < G) {
        const int g = t;
        float mx = -1e30f;
        for (int j = 0; j < KNN; j++) mx = fmaxf(mx, wl[j * G + g]);
        float e[KNN], sum = 0.f;
        for (int j = 0; j < KNN; j++) { e[j] = __expf(wl[j * G + g] - mx); sum += e[j]; }
        const float inv = 1.f / sum;
        for (int j = 0; j < KNN; j++) wfin[j * G + g] = e[j] * inv * mfs[j];
    }
    __syncthreads();

    // ---- stage 4: out[m][c] = sum_j val[j][c] * w[j][c>>4] ----
    if (t < C) {
        const int c = t, g = c >> 4;
        float acc = 0.f;
#pragma unroll
        for (int j = 0; j < KNN; j++)
            acc = fmaf(val[j * CP + c], wfin[j * G + g], acc);
        out[(long long)m * C + c] = acc;
    }
}

// ---------------------------------------------------------------------------
extern "C" void kernel_launch(void* const* d_in, const int* in_sizes, int n_in,
                              void* d_out, int out_size, void* d_ws, size_t ws_size,
                              hipStream_t stream)
{
    const float* query_feat    = (const float*)d_in[0];
    const float* context_feat  = (const float*)d_in[1];
    const float* query_coord   = (const float*)d_in[2];
    const float* context_coord = (const float*)d_in[3];
    const float* Wq    = (const float*)d_in[4];
    const float* bq    = (const float*)d_in[5];
    const float* gq    = (const float*)d_in[6];
    const float* betaq = (const float*)d_in[7];
    const float* Wk    = (const float*)d_in[8];
    const float* bk    = (const float*)d_in[9];
    const float* gk    = (const float*)d_in[10];
    const float* betak = (const float*)d_in[11];
    const float* Wv    = (const float*)d_in[12];
    const float* bv    = (const float*)d_in[13];
    const float* Wp1   = (const float*)d_in[14];
    const float* bp1   = (const float*)d_in[15];
    const float* gp1   = (const float*)d_in[16];
    const float* betap1= (const float*)d_in[17];
    const float* Wp2   = (const float*)d_in[18];
    const float* bp2   = (const float*)d_in[19];
    const float* Ww1   = (const float*)d_in[20];
    const float* bw1   = (const float*)d_in[21];
    const float* gw1   = (const float*)d_in[22];
    const float* betaw1= (const float*)d_in[23];
    const float* Ww2   = (const float*)d_in[24];
    const float* bw2   = (const float*)d_in[25];
    const int*   knn   = (const int*)d_in[26];

    const int M = in_sizes[0] / C;   // 16384
    const int N = in_sizes[1] / C;   // 131072

    // workspace layout: k (N*C) | v (N*C) | q (M*C)  -- 142.6 MB fp32
    float* kbuf = (float*)d_ws;
    float* vbuf = kbuf + (size_t)N * C;
    float* qbuf = vbuf + (size_t)N * C;

    kv_kernel<8><<<N / 8, 256, 0, stream>>>(context_feat, Wk, bk, gk, betak,
                                            Wv, bv, kbuf, vbuf);
    q_kernel<8><<<M / 8, 256, 0, stream>>>(query_feat, Wq, bq, gq, betaq, qbuf);
    attn_kernel<<<M, 256, 0, stream>>>(qbuf, kbuf, vbuf, query_coord, context_coord,
                                       Wp1, bp1, gp1, betap1, Wp2, bp2,
                                       Ww1, bw1, gw1, betaw1, Ww2, bw2,
                                       knn, (float*)d_out);
}

// Round 2
// 279.434 us; speedup vs baseline: 1.9476x; 1.9476x over previous
//
#include <hip/hip_runtime.h>

#define C 128
#define G 8
#define KNN 16
#define QB 4
#define EPS 1e-5f

typedef unsigned short u16;
typedef __attribute__((ext_vector_type(8))) short short8;   // 8 bf16 = 4 VGPRs
typedef __attribute__((ext_vector_type(4))) float float4v;  // MFMA accumulator

union frag_u { short8 v; u16 u[8]; };

__device__ inline u16 f2bf(float f) {
    unsigned u = __builtin_bit_cast(unsigned, f);
    unsigned r = (u + 0x7fffu + ((u >> 16) & 1u)) >> 16;
    return (u16)r;
}
__device__ inline float bf2f(u16 h) {
    unsigned u = ((unsigned)h) << 16;
    return __builtin_bit_cast(float, u);
}

// ---------------------------------------------------------------------------
// MFMA projection: out1 = relu(bn(X@W1 + b1)) [bf16], optional out2 = X@W2+b2.
// Block: 256 thr = 4 waves, 64 rows of X. Wave w owns output cols [32w,32w+32).
// A-frag (16x16x32): A[m=lane&15][k=quad*8+j]; B-frag: B[k=quad*8+j][n=lane&15];
// C/D: col=lane&15, row=quad*4+reg.
// ---------------------------------------------------------------------------
template <int TWO>
__global__ __launch_bounds__(256) void proj_mfma(
    const float* __restrict__ X,
    const float* __restrict__ W1, const float* __restrict__ b1,
    const float* __restrict__ g1, const float* __restrict__ be1,
    const float* __restrict__ W2, const float* __restrict__ b2,
    u16* __restrict__ out1, u16* __restrict__ out2)
{
    __shared__ u16 Xs[64 * 136];          // bf16, row stride 136 (pad 8)
    const int t = threadIdx.x;
    const int w = t >> 6, l = t & 63;
    const int row0 = blockIdx.x * 64;

    // stage X tile -> bf16 LDS
    {
        const float4* Xv = (const float4*)(X + (size_t)row0 * C);
#pragma unroll
        for (int i = 0; i < 8; i++) {
            const int e = t + 256 * i;          // float4 index 0..2047
            const int r = e >> 5, c4 = e & 31;
            const float4 f = Xv[e];
            unsigned lo = (unsigned)f2bf(f.x) | ((unsigned)f2bf(f.y) << 16);
            unsigned hi = (unsigned)f2bf(f.z) | ((unsigned)f2bf(f.w) << 16);
            uint2 p; p.x = lo; p.y = hi;
            *(uint2*)(&Xs[r * 136 + c4 * 4]) = p;
        }
    }

    // B fragments from global (L2-hot): [w2][ct][kk]
    frag_u Bf[TWO + 1][2][4];
    const int quad = l >> 4, lan = l & 15;
#pragma unroll
    for (int w2 = 0; w2 <= TWO; w2++) {
        const float* Wp = w2 ? W2 : W1;
#pragma unroll
        for (int ct = 0; ct < 2; ct++) {
            const int cg = w * 32 + ct * 16 + lan;
#pragma unroll
            for (int kk = 0; kk < 4; kk++) {
#pragma unroll
                for (int j = 0; j < 8; j++)
                    Bf[w2][ct][kk].u[j] = f2bf(Wp[(kk * 32 + quad * 8 + j) * C + cg]);
            }
        }
    }
    __syncthreads();

    float4v acc[TWO + 1][2][4];   // [w2][ct][rt]
#pragma unroll
    for (int w2 = 0; w2 <= TWO; w2++)
#pragma unroll
        for (int ct = 0; ct < 2; ct++)
#pragma unroll
            for (int rt = 0; rt < 4; rt++)
                acc[w2][ct][rt] = (float4v)0.f;

#pragma unroll
    for (int rt = 0; rt < 4; rt++) {
#pragma unroll
        for (int kk = 0; kk < 4; kk++) {
            const short8 A = *(const short8*)(&Xs[(rt * 16 + lan) * 136 + kk * 32 + quad * 8]);
#pragma unroll
            for (int w2 = 0; w2 <= TWO; w2++)
#pragma unroll
                for (int ct = 0; ct < 2; ct++)
                    acc[w2][ct][rt] = __builtin_amdgcn_mfma_f32_16x16x32_bf16(
                        A, Bf[w2][ct][kk].v, acc[w2][ct][rt], 0, 0, 0);
        }
    }

    // epilogue
#pragma unroll
    for (int ct = 0; ct < 2; ct++) {
        const int cg = w * 32 + ct * 16 + lan;
        const float bb = b1[cg];
        const float sc = g1[cg] * rsqrtf(1.f + EPS);
        const float sh = be1[cg];
#pragma unroll
        for (int rt = 0; rt < 4; rt++)
#pragma unroll
            for (int reg = 0; reg < 4; reg++) {
                const int rg = row0 + rt * 16 + quad * 4 + reg;
                float y = (acc[0][ct][rt][reg] + bb) * sc + sh;
                y = y > 0.f ? y : 0.f;
                out1[(size_t)rg * C + cg] = f2bf(y);
            }
        if (TWO) {
            const float bv = b2[cg];
#pragma unroll
            for (int rt = 0; rt < 4; rt++)
#pragma unroll
                for (int reg = 0; reg < 4; reg++) {
                    const int rg = row0 + rt * 16 + quad * 4 + reg;
                    out2[(size_t)rg * C + cg] = f2bf(acc[1][ct][rt][reg] + bv);
                }
        }
    }
}

// ---------------------------------------------------------------------------
// Attention v2: QB=4 queries per block (64 neighbor-rows), peb GEMM via MFMA.
// ---------------------------------------------------------------------------
__global__ __launch_bounds__(256) void attn2(
    const u16* __restrict__ qbuf,     // M x C bf16
    const u16* __restrict__ kbuf,     // N x C bf16
    const u16* __restrict__ vbuf,     // N x C bf16
    const float* __restrict__ qcoord, const float* __restrict__ ccoord,
    const float* __restrict__ Wp1, const float* __restrict__ bp1,
    const float* __restrict__ gp1, const float* __restrict__ betap1,
    const float* __restrict__ Wp2, const float* __restrict__ bp2,
    const float* __restrict__ Ww1, const float* __restrict__ bw1,
    const float* __restrict__ gw1, const float* __restrict__ betaw1,
    const float* __restrict__ Ww2, const float* __restrict__ bw2,
    const int* __restrict__ knn,
    float* __restrict__ out)
{
    __shared__ u16   h1s[64 * 136];     // h1 bf16 (A-frag layout), later: val bf16
    __shared__ float relbuf[64 * 132];  // peb, then rel (pad 4)
    __shared__ float qs[QB * C];
    __shared__ float w1s[C * G];
    __shared__ float pxs[64], pys[64], pzs[64], mfs[64];
    __shared__ int   idxs[64];
    __shared__ float hws[QB * 16 * G];
    __shared__ float wl[QB * 16 * G];

    const int t = threadIdx.x;
    const int w = t >> 6, l = t & 63;
    const int quad = l >> 4, lan = l & 15;
    const int m0 = blockIdx.x * QB;

    // ---- S0: indices, rel positions, q rows, Ww1 ----
    if (t < 64) {
        const int q = t >> 4;
        const int gi = knn[(m0 + q) * KNN + (t & 15)];
        const float mf = gi >= 0 ? 1.f : 0.f;
        const int i0 = gi >= 0 ? gi : 0;
        idxs[t] = i0; mfs[t] = mf;
        pxs[t] = (ccoord[i0 * 3 + 0] - qcoord[(m0 + q) * 3 + 0]) * mf;
        pys[t] = (ccoord[i0 * 3 + 1] - qcoord[(m0 + q) * 3 + 1]) * mf;
        pzs[t] = (ccoord[i0 * 3 + 2] - qcoord[(m0 + q) * 3 + 2]) * mf;
    }
#pragma unroll
    for (int i = 0; i < 2; i++) {
        const int e = t + 256 * i;
        qs[e] = bf2f(qbuf[(size_t)(m0 + (e >> 7)) * C + (e & 127)]);
    }
    ((float4*)w1s)[t] = ((const float4*)Ww1)[t];
    __syncthreads();

    // ---- S1: h1 = relu(bn(pos @ Wp1 + bp1)) -> bf16 LDS (A-frag layout) ----
    {
        const int c = t & 127, hh = t >> 7;
        const float w0 = Wp1[c], w1 = Wp1[C + c], w2 = Wp1[2 * C + c];
        const float sc = gp1[c] * rsqrtf(1.f + EPS);
        const float bb = bp1[c], sh = betap1[c];
#pragma unroll
        for (int r2 = 0; r2 < 32; r2++) {
            const int r = hh * 32 + r2;
            float y = fmaf(pxs[r], w0, fmaf(pys[r], w1, fmaf(pzs[r], w2, bb)));
            y = y * sc + sh;
            y = y > 0.f ? y : 0.f;
            h1s[r * 136 + c] = f2bf(y);
        }
    }
    __syncthreads();

    // ---- S2: peb = h1 @ Wp2  (MFMA), scatter to relbuf ----
    {
        frag_u Bf[2][4];
#pragma unroll
        for (int ct = 0; ct < 2; ct++) {
            const int cg = w * 32 + ct * 16 + lan;
#pragma unroll
            for (int kk = 0; kk < 4; kk++)
#pragma unroll
                for (int j = 0; j < 8; j++)
                    Bf[ct][kk].u[j] = f2bf(Wp2[(kk * 32 + quad * 8 + j) * C + cg]);
        }
        float4v acc[2][4];
#pragma unroll
        for (int ct = 0; ct < 2; ct++)
#pragma unroll
            for (int q = 0; q < 4; q++) acc[ct][q] = (float4v)0.f;

#pragma unroll
        for (int q = 0; q < 4; q++) {
#pragma unroll
            for (int kk = 0; kk < 4; kk++) {
                const short8 A = *(const short8*)(&h1s[(q * 16 + lan) * 136 + kk * 32 + quad * 8]);
#pragma unroll
                for (int ct = 0; ct < 2; ct++)
                    acc[ct][q] = __builtin_amdgcn_mfma_f32_16x16x32_bf16(
                        A, Bf[ct][kk].v, acc[ct][q], 0, 0, 0);
            }
        }
        const float bb0 = bp2[w * 32 + lan];
        const float bb1 = bp2[w * 32 + 16 + lan];
#pragma unroll
        for (int ct = 0; ct < 2; ct++)
#pragma unroll
            for (int q = 0; q < 4; q++)
#pragma unroll
                for (int reg = 0; reg < 4; reg++)
                    relbuf[(q * 16 + quad * 4 + reg) * 132 + w * 32 + ct * 16 + lan] =
                        acc[ct][q][reg] + (ct ? bb1 : bb0);
    }
    __syncthreads();

    // ---- S3: gather k/v, rel = kg*mf - q + peb (in place), val -> h1s bf16 ----
    {
        const int c = t & 127, hh = t >> 7;
        float qv[QB];
#pragma unroll
        for (int q = 0; q < QB; q++) qv[q] = qs[q * C + c];
#pragma unroll
        for (int q = 0; q < QB; q++) {
#pragma unroll
            for (int jj = 0; jj < 8; jj++) {
                const int row = q * 16 + hh * 8 + jj;
                const int gi = idxs[row];
                const float mf = mfs[row];
                const float kg = bf2f(kbuf[(size_t)gi * C + c]);
                const float vg = bf2f(vbuf[(size_t)gi * C + c]);
                const float peb = relbuf[row * 132 + c];
                relbuf[row * 132 + c] = fmaf(kg, mf, peb - qv[q]);
                h1s[row * 136 + c] = f2bf(fmaf(vg, mf, peb));
            }
        }
    }
    __syncthreads();

    // ---- S4: hw = relu(bn(rel @ Ww1 + bw1)) ----
#pragma unroll
    for (int i = 0; i < 2; i++) {
        const int s = t + 256 * i;
        const int q = s >> 7, j = (s >> 3) & 15, g = s & 7;
        float a = 0.f;
#pragma unroll 8
        for (int cc = 0; cc < C; cc++)
            a = fmaf(relbuf[(q * 16 + j) * 132 + cc], w1s[cc * G + g], a);
        const float sc = gw1[g] * rsqrtf(1.f + EPS);
        float y = (a + bw1[g]) * sc + betaw1[g];
        hws[s] = y > 0.f ? y : 0.f;
    }
    __syncthreads();

    // ---- S5: logits = hw @ Ww2 + bw2 ----
#pragma unroll
    for (int i = 0; i < 2; i++) {
        const int s = t + 256 * i;
        const int q = s >> 7, j = (s >> 3) & 15, g = s & 7;
        float a = bw2[g];
#pragma unroll
        for (int gg = 0; gg < G; gg++)
            a = fmaf(hws[q * 128 + j * 8 + gg], Ww2[gg * G + g], a);
        wl[s] = a;
    }
    __syncthreads();

    // ---- softmax over neighbors per (q, g), * mask ----
    if (t < QB * G) {
        const int q = t >> 3, g = t & 7;
        float mx = -1e30f;
#pragma unroll
        for (int j = 0; j < KNN; j++) mx = fmaxf(mx, wl[q * 128 + j * 8 + g]);
        float e[KNN], sum = 0.f;
#pragma unroll
        for (int j = 0; j < KNN; j++) {
            e[j] = __expf(wl[q * 128 + j * 8 + g] - mx);
            sum += e[j];
        }
        const float inv = 1.f / sum;
#pragma unroll
        for (int j = 0; j < KNN; j++)
            wl[q * 128 + j * 8 + g] = e[j] * inv * mfs[q * 16 + j];
    }
    __syncthreads();

    // ---- S6: out[q][c] = sum_j val[j][c] * w[j][c>>4] ----
#pragma unroll
    for (int i = 0; i < 2; i++) {
        const int e = t + 256 * i;
        const int q = e >> 7, c = e & 127, g = c >> 4;
        float a = 0.f;
#pragma unroll
        for (int j = 0; j < KNN; j++)
            a = fmaf(bf2f(h1s[(q * 16 + j) * 136 + c]), wl[q * 128 + j * 8 + g], a);
        out[(size_t)(m0 + q) * C + c] = a;
    }
}

// ---------------------------------------------------------------------------
extern "C" void kernel_launch(void* const* d_in, const int* in_sizes, int n_in,
                              void* d_out, int out_size, void* d_ws, size_t ws_size,
                              hipStream_t stream)
{
    const float* query_feat    = (const float*)d_in[0];
    const float* context_feat  = (const float*)d_in[1];
    const float* query_coord   = (const float*)d_in[2];
    const float* context_coord = (const float*)d_in[3];
    const float* Wq    = (const float*)d_in[4];
    const float* bq    = (const float*)d_in[5];
    const float* gq    = (const float*)d_in[6];
    const float* betaq = (const float*)d_in[7];
    const float* Wk    = (const float*)d_in[8];
    const float* bk    = (const float*)d_in[9];
    const float* gk    = (const float*)d_in[10];
    const float* betak = (const float*)d_in[11];
    const float* Wv    = (const float*)d_in[12];
    const float* bv    = (const float*)d_in[13];
    const float* Wp1   = (const float*)d_in[14];
    const float* bp1   = (const float*)d_in[15];
    const float* gp1   = (const float*)d_in[16];
    const float* betap1= (const float*)d_in[17];
    const float* Wp2   = (const float*)d_in[18];
    const float* bp2   = (const float*)d_in[19];
    const float* Ww1   = (const float*)d_in[20];
    const float* bw1   = (const float*)d_in[21];
    const float* gw1   = (const float*)d_in[22];
    const float* betaw1= (const float*)d_in[23];
    const float* Ww2   = (const float*)d_in[24];
    const float* bw2   = (const float*)d_in[25];
    const int*   knn   = (const int*)d_in[26];

    const int M = in_sizes[0] / C;   // 16384
    const int N = in_sizes[1] / C;   // 131072

    // workspace: k (N*C bf16) | v (N*C bf16) | q (M*C bf16)
    u16* kb = (u16*)d_ws;
    u16* vb = kb + (size_t)N * C;
    u16* qb = vb + (size_t)N * C;

    proj_mfma<1><<<N / 64, 256, 0, stream>>>(context_feat, Wk, bk, gk, betak,
                                             Wv, bv, kb, vb);
    proj_mfma<0><<<M / 64, 256, 0, stream>>>(query_feat, Wq, bq, gq, betaq,
                                             nullptr, nullptr, qb, nullptr);
    attn2<<<M / QB, 256, 0, stream>>>(qb, kb, vb, query_coord, context_coord,
                                      Wp1, bp1, gp1, betap1, Wp2, bp2,
                                      Ww1, bw1, gw1, betaw1, Ww2, bw2,
                                      knn, (float*)d_out);
}

// Round 3
// 236.281 us; speedup vs baseline: 2.3033x; 1.1826x over previous
//
#include <hip/hip_runtime.h>

#define C 128
#define G 8
#define KNN 16
#define QB 4
#define EPS 1e-5f

typedef unsigned short u16;
typedef __attribute__((ext_vector_type(8))) short short8;   // 8 bf16 = 4 VGPRs
typedef __attribute__((ext_vector_type(4))) float float4v;  // MFMA accumulator

union frag_u { short8 v; u16 u[8]; };

__device__ inline u16 f2bf(float f) {
    unsigned u = __builtin_bit_cast(unsigned, f);
    unsigned r = (u + 0x7fffu + ((u >> 16) & 1u)) >> 16;
    return (u16)r;
}
__device__ inline float bf2f(u16 h) {
    unsigned u = ((unsigned)h) << 16;
    return __builtin_bit_cast(float, u);
}

// ---------------------------------------------------------------------------
// Prep: swizzle weights into MFMA B-fragment-ready bf16 layout.
// 128x128 W -> [cb 8][kk 4][quad 4][lan 16][j 8] u16 (16384)
//   element = W[k=kk*32+quad*8+j][n=cb*16+lan]
// Ww1 128x8 -> [kk 4][quad 4][lan 16][j 8] u16 (4096), zero for lan>=8
// ---------------------------------------------------------------------------
__global__ __launch_bounds__(256) void prep_w(
    const float* __restrict__ Wk, const float* __restrict__ Wv,
    const float* __restrict__ Wq, const float* __restrict__ Wp2,
    const float* __restrict__ Ww1, u16* __restrict__ dst)
{
    const int b = blockIdx.x, t = threadIdx.x;
    if (b < 4) {
        const float* W = b == 0 ? Wk : b == 1 ? Wv : b == 2 ? Wq : Wp2;
        u16* d = dst + b * 16384;
        for (int e = t; e < 16384; e += 256) {
            const int k = e >> 7, n = e & 127;
            const int cb = n >> 4, lan = n & 15;
            const int kk = k >> 5, quad = (k >> 3) & 3, j = k & 7;
            d[(((cb * 4 + kk) * 4 + quad) * 16 + lan) * 8 + j] = f2bf(W[e]);
        }
    } else {
        u16* d = dst + 4 * 16384;
        for (int e = t; e < 4096; e += 256) {
            const int j = e & 7, lan = (e >> 3) & 15;
            const int quad = (e >> 7) & 3, kk = e >> 9;
            const int k = kk * 32 + quad * 8 + j;
            d[e] = lan < 8 ? f2bf(Ww1[k * G + lan]) : (u16)0;
        }
    }
}

// ---------------------------------------------------------------------------
// MFMA projection with prepped B fragments.
// Block: 4 waves, 64 rows. Wave w owns cols [32w, 32w+32).
// ---------------------------------------------------------------------------
template <int TWO>
__global__ __launch_bounds__(256) void proj_mfma(
    const float* __restrict__ X,
    const u16* __restrict__ PW1, const float* __restrict__ b1,
    const float* __restrict__ g1, const float* __restrict__ be1,
    const u16* __restrict__ PW2, const float* __restrict__ b2,
    u16* __restrict__ out1, u16* __restrict__ out2)
{
    __shared__ u16 Xs[64 * 136];
    const int t = threadIdx.x;
    const int w = t >> 6, l = t & 63;
    const int quad = l >> 4, lan = l & 15;
    const int row0 = blockIdx.x * 64;

    // stage X tile -> bf16 LDS
    {
        const float4* Xv = (const float4*)(X + (size_t)row0 * C);
#pragma unroll
        for (int i = 0; i < 8; i++) {
            const int e = t + 256 * i;
            const int r = e >> 5, c4 = e & 31;
            const float4 f = Xv[e];
            uint2 p;
            p.x = (unsigned)f2bf(f.x) | ((unsigned)f2bf(f.y) << 16);
            p.y = (unsigned)f2bf(f.z) | ((unsigned)f2bf(f.w) << 16);
            *(uint2*)(&Xs[r * 136 + c4 * 4]) = p;
        }
    }

    // B fragments: one dwordx4 per (w2, ct, kk)
    short8 Bf[TWO + 1][2][4];
#pragma unroll
    for (int w2 = 0; w2 <= TWO; w2++) {
        const u16* P = w2 ? PW2 : PW1;
#pragma unroll
        for (int ct = 0; ct < 2; ct++) {
            const int cb = w * 2 + ct;
#pragma unroll
            for (int kk = 0; kk < 4; kk++)
                Bf[w2][ct][kk] = *(const short8*)(P + (((cb * 4 + kk) * 4 + quad) * 16 + lan) * 8);
        }
    }
    __syncthreads();

    float4v acc[TWO + 1][2][4];
#pragma unroll
    for (int w2 = 0; w2 <= TWO; w2++)
#pragma unroll
        for (int ct = 0; ct < 2; ct++)
#pragma unroll
            for (int rt = 0; rt < 4; rt++)
                acc[w2][ct][rt] = (float4v)0.f;

#pragma unroll
    for (int rt = 0; rt < 4; rt++) {
#pragma unroll
        for (int kk = 0; kk < 4; kk++) {
            const short8 A = *(const short8*)(&Xs[(rt * 16 + lan) * 136 + kk * 32 + quad * 8]);
#pragma unroll
            for (int w2 = 0; w2 <= TWO; w2++)
#pragma unroll
                for (int ct = 0; ct < 2; ct++)
                    acc[w2][ct][rt] = __builtin_amdgcn_mfma_f32_16x16x32_bf16(
                        A, Bf[w2][ct][kk], acc[w2][ct][rt], 0, 0, 0);
        }
    }

    // epilogue: bn+relu on out1, plain bias on out2
#pragma unroll
    for (int ct = 0; ct < 2; ct++) {
        const int cg = w * 32 + ct * 16 + lan;
        const float bb = b1[cg];
        const float sc = g1[cg] * rsqrtf(1.f + EPS);
        const float sh = be1[cg];
#pragma unroll
        for (int rt = 0; rt < 4; rt++)
#pragma unroll
            for (int reg = 0; reg < 4; reg++) {
                const int rg = row0 + rt * 16 + quad * 4 + reg;
                float y = (acc[0][ct][rt][reg] + bb) * sc + sh;
                y = y > 0.f ? y : 0.f;
                out1[(size_t)rg * C + cg] = f2bf(y);
            }
        if (TWO) {
            const float bv = b2[cg];
#pragma unroll
            for (int rt = 0; rt < 4; rt++)
#pragma unroll
                for (int reg = 0; reg < 4; reg++) {
                    const int rg = row0 + rt * 16 + quad * 4 + reg;
                    out2[(size_t)rg * C + cg] = f2bf(acc[1][ct][rt][reg] + bv);
                }
        }
    }
}

// ---------------------------------------------------------------------------
// Attention v3: QB=4 queries/block, 39.9 KB LDS -> 4 blocks/CU.
// peb/rel stored bf16; rel@Ww1 via MFMA; k/v gathers prefetched to registers.
// ---------------------------------------------------------------------------
__global__ __launch_bounds__(256) void attn3(
    const u16* __restrict__ qbuf, const u16* __restrict__ kbuf,
    const u16* __restrict__ vbuf,
    const float* __restrict__ qcoord, const float* __restrict__ ccoord,
    const float* __restrict__ Wp1, const float* __restrict__ bp1,
    const float* __restrict__ gp1, const float* __restrict__ betap1,
    const u16* __restrict__ PWp2, const float* __restrict__ bp2,
    const u16* __restrict__ PWw1, const float* __restrict__ bw1,
    const float* __restrict__ gw1, const float* __restrict__ betaw1,
    const float* __restrict__ Ww2, const float* __restrict__ bw2,
    const int* __restrict__ knn, float* __restrict__ out)
{
    __shared__ u16   fA[64 * 136];    // h1 (A-frag bf16), later val
    __shared__ u16   relB[64 * 136];  // peb (bf16, C-layout scatter), then rel
    __shared__ float pxs[64], pys[64], pzs[64], mfs[64];
    __shared__ float wl[QB * 16 * G];   // hw
    __shared__ float wfin[QB * 16 * G]; // softmax weights

    const int t = threadIdx.x;
    const int w = t >> 6, l = t & 63;
    const int quad = l >> 4, lan = l & 15;
    const int m0 = blockIdx.x * QB;

    // ---- prefetch k/v gathers (rows p*16+rsub, cols c8..c8+8) ----
    const int rsub = t >> 4;
    const int c8 = (t & 15) * 8;
    float mfr[4];
    frag_u kg[4], vg[4];
#pragma unroll
    for (int p = 0; p < 4; p++) {
        const int ii = knn[m0 * KNN + p * 16 + rsub];
        mfr[p] = ii >= 0 ? 1.f : 0.f;
        const int i0 = ii >= 0 ? ii : 0;
        kg[p].v = *(const short8*)(kbuf + (size_t)i0 * C + c8);
        vg[p].v = *(const short8*)(vbuf + (size_t)i0 * C + c8);
    }

    // ---- S0: relative positions ----
    if (t < 64) {
        const int q = t >> 4;
        const int ii = knn[m0 * KNN + t];
        const float mf = ii >= 0 ? 1.f : 0.f;
        const int i0 = ii >= 0 ? ii : 0;
        mfs[t] = mf;
        pxs[t] = (ccoord[i0 * 3 + 0] - qcoord[(m0 + q) * 3 + 0]) * mf;
        pys[t] = (ccoord[i0 * 3 + 1] - qcoord[(m0 + q) * 3 + 1]) * mf;
        pzs[t] = (ccoord[i0 * 3 + 2] - qcoord[(m0 + q) * 3 + 2]) * mf;
    }
    __syncthreads();

    // ---- S1: h1 = relu(bn(pos @ Wp1 + bp1)) -> fA bf16 (A-frag layout) ----
    {
        const int c = t & 127, hh = t >> 7;
        const float w0 = Wp1[c], w1_ = Wp1[C + c], w2_ = Wp1[2 * C + c];
        const float sc = gp1[c] * rsqrtf(1.f + EPS);
        const float bb = bp1[c], sh = betap1[c];
#pragma unroll
        for (int r2 = 0; r2 < 32; r2++) {
            const int r = hh * 32 + r2;
            float y = fmaf(pxs[r], w0, fmaf(pys[r], w1_, fmaf(pzs[r], w2_, bb)));
            y = y * sc + sh;
            y = y > 0.f ? y : 0.f;
            fA[r * 136 + c] = f2bf(y);
        }
    }
    __syncthreads();

    // ---- S2: peb = h1 @ Wp2 (MFMA), scatter bf16 into relB ----
    {
        short8 Bf[2][4];
#pragma unroll
        for (int ct = 0; ct < 2; ct++) {
            const int cb = w * 2 + ct;
#pragma unroll
            for (int kk = 0; kk < 4; kk++)
                Bf[ct][kk] = *(const short8*)(PWp2 + (((cb * 4 + kk) * 4 + quad) * 16 + lan) * 8);
        }
        float4v acc[2][4];
#pragma unroll
        for (int ct = 0; ct < 2; ct++)
#pragma unroll
            for (int q = 0; q < 4; q++) acc[ct][q] = (float4v)0.f;

#pragma unroll
        for (int q = 0; q < 4; q++) {
#pragma unroll
            for (int kk = 0; kk < 4; kk++) {
                const short8 A = *(const short8*)(&fA[(q * 16 + lan) * 136 + kk * 32 + quad * 8]);
#pragma unroll
                for (int ct = 0; ct < 2; ct++)
                    acc[ct][q] = __builtin_amdgcn_mfma_f32_16x16x32_bf16(
                        A, Bf[ct][kk], acc[ct][q], 0, 0, 0);
            }
        }
        const float bb0 = bp2[w * 32 + lan];
        const float bb1 = bp2[w * 32 + 16 + lan];
#pragma unroll
        for (int ct = 0; ct < 2; ct++)
#pragma unroll
            for (int q = 0; q < 4; q++)
#pragma unroll
                for (int reg = 0; reg < 4; reg++)
                    relB[(q * 16 + quad * 4 + reg) * 136 + w * 32 + ct * 16 + lan] =
                        f2bf(acc[ct][q][reg] + (ct ? bb1 : bb0));
    }
    __syncthreads();

    // ---- S3: rel = kg*mf - q + peb (in place), val = vg*mf + peb -> fA ----
    {
#pragma unroll
        for (int p = 0; p < 4; p++) {
            const int r = p * 16 + rsub;
            const float mf = mfr[p];
            frag_u qg, peb, relv, valv;
            qg.v  = *(const short8*)(qbuf + (size_t)(m0 + p) * C + c8);
            peb.v = *(const short8*)(&relB[r * 136 + c8]);
#pragma unroll
            for (int j = 0; j < 8; j++) {
                const float pe = bf2f(peb.u[j]);
                relv.u[j] = f2bf(fmaf(bf2f(kg[p].u[j]), mf, pe - bf2f(qg.u[j])));
                valv.u[j] = f2bf(fmaf(bf2f(vg[p].u[j]), mf, pe));
            }
            *(short8*)(&relB[r * 136 + c8]) = relv.v;
            *(short8*)(&fA[r * 136 + c8])  = valv.v;
        }
    }
    __syncthreads();

    // ---- S4: hw = relu(bn(rel @ Ww1 + bw1)) via MFMA; wave w -> query w ----
    {
        short8 Bw[4];
#pragma unroll
        for (int kk = 0; kk < 4; kk++)
            Bw[kk] = *(const short8*)(PWw1 + ((kk * 4 + quad) * 16 + lan) * 8);
        float4v acc = (float4v)0.f;
#pragma unroll
        for (int kk = 0; kk < 4; kk++) {
            const short8 A = *(const short8*)(&relB[(w * 16 + lan) * 136 + kk * 32 + quad * 8]);
            acc = __builtin_amdgcn_mfma_f32_16x16x32_bf16(A, Bw[kk], acc, 0, 0, 0);
        }
        if (lan < G) {
            const int g = lan;
            const float sc = gw1[g] * rsqrtf(1.f + EPS);
            const float bb = bw1[g], sh = betaw1[g];
#pragma unroll
            for (int reg = 0; reg < 4; reg++) {
                const int j = quad * 4 + reg;
                float y = (acc[reg] + bb) * sc + sh;
                wl[w * 128 + j * 8 + g] = y > 0.f ? y : 0.f;
            }
        }
    }
    __syncthreads();

    // ---- S5: logits = hw @ Ww2 + bw2; softmax over neighbors; * mask ----
    if (t < QB * G) {
        const int q = t >> 3, g2 = t & 7;
        float w2c[G];
#pragma unroll
        for (int g = 0; g < G; g++) w2c[g] = Ww2[g * G + g2];
        const float bb = bw2[g2];
        float lg[KNN], mx = -1e30f;
#pragma unroll
        for (int j = 0; j < KNN; j++) {
            float a = bb;
#pragma unroll
            for (int g = 0; g < G; g++) a = fmaf(wl[q * 128 + j * 8 + g], w2c[g], a);
            lg[j] = a;
            mx = fmaxf(mx, a);
        }
        float sum = 0.f;
#pragma unroll
        for (int j = 0; j < KNN; j++) { lg[j] = __expf(lg[j] - mx); sum += lg[j]; }
        const float inv = 1.f / sum;
#pragma unroll
        for (int j = 0; j < KNN; j++)
            wfin[q * 128 + j * 8 + g2] = lg[j] * inv * mfs[q * 16 + j];
    }
    __syncthreads();

    // ---- S6: out[q][c] = sum_j val[j][c] * w[j][c>>4] ----
#pragma unroll
    for (int i = 0; i < 2; i++) {
        const int e = t + 256 * i;
        const int q = e >> 7, c = e & 127, g = c >> 4;
        float a = 0.f;
#pragma unroll
        for (int j = 0; j < KNN; j++)
            a = fmaf(bf2f(fA[(q * 16 + j) * 136 + c]), wfin[q * 128 + j * 8 + g], a);
        out[(size_t)(m0 + q) * C + c] = a;
    }
}

// ---------------------------------------------------------------------------
extern "C" void kernel_launch(void* const* d_in, const int* in_sizes, int n_in,
                              void* d_out, int out_size, void* d_ws, size_t ws_size,
                              hipStream_t stream)
{
    const float* query_feat    = (const float*)d_in[0];
    const float* context_feat  = (const float*)d_in[1];
    const float* query_coord   = (const float*)d_in[2];
    const float* context_coord = (const float*)d_in[3];
    const float* Wq    = (const float*)d_in[4];
    const float* bq    = (const float*)d_in[5];
    const float* gq    = (const float*)d_in[6];
    const float* betaq = (const float*)d_in[7];
    const float* Wk    = (const float*)d_in[8];
    const float* bk    = (const float*)d_in[9];
    const float* gk    = (const float*)d_in[10];
    const float* betak = (const float*)d_in[11];
    const float* Wv    = (const float*)d_in[12];
    const float* bv    = (const float*)d_in[13];
    const float* Wp1   = (const float*)d_in[14];
    const float* bp1   = (const float*)d_in[15];
    const float* gp1   = (const float*)d_in[16];
    const float* betap1= (const float*)d_in[17];
    const float* Wp2   = (const float*)d_in[18];
    const float* bp2   = (const float*)d_in[19];
    const float* Ww1   = (const float*)d_in[20];
    const float* bw1   = (const float*)d_in[21];
    const float* gw1   = (const float*)d_in[22];
    const float* betaw1= (const float*)d_in[23];
    const float* Ww2   = (const float*)d_in[24];
    const float* bw2   = (const float*)d_in[25];
    const int*   knn   = (const int*)d_in[26];

    const int M = in_sizes[0] / C;   // 16384
    const int N = in_sizes[1] / C;   // 131072

    // workspace: k | v | q (bf16) | prepped weights
    u16* kb = (u16*)d_ws;
    u16* vb = kb + (size_t)N * C;
    u16* qb = vb + (size_t)N * C;
    u16* pw = qb + (size_t)M * C;    // Wk,Wv,Wq,Wp2 (4*16384) + Ww1 (4096)
    u16* pWk  = pw;
    u16* pWv  = pw + 16384;
    u16* pWq  = pw + 2 * 16384;
    u16* pWp2 = pw + 3 * 16384;
    u16* pWw1 = pw + 4 * 16384;

    prep_w<<<5, 256, 0, stream>>>(Wk, Wv, Wq, Wp2, Ww1, pw);
    proj_mfma<1><<<N / 64, 256, 0, stream>>>(context_feat, pWk, bk, gk, betak,
                                             pWv, bv, kb, vb);
    proj_mfma<0><<<M / 64, 256, 0, stream>>>(query_feat, pWq, bq, gq, betaq,
                                             nullptr, nullptr, qb, nullptr);
    attn3<<<M / QB, 256, 0, stream>>>(qb, kb, vb, query_coord, context_coord,
                                      Wp1, bp1, gp1, betap1, pWp2, bp2,
                                      pWw1, bw1, gw1, betaw1, Ww2, bw2,
                                      knn, (float*)d_out);
}